// Round 5
// baseline (199.739 us; speedup 1.0000x reference)
//
#include <hip/hip_runtime.h>

// GlobalLocalPool: B=16, T=4096, H=512, fp32 in/out.
// out[b, 0:H]   = sum_{t < len[b]}  x[b,t,:] / max(len[b],1)
// out[b, H:2H]  = sum_{mask[b,t]}   x[b,t,:] / max(popcount(mask[b]),1)
// (span-compaction in the reference == plain masked mean; mask arrives as int32.)
//
// R4 lesson: batch-of-8 loads with a full vmcnt(0) stall between batches left
// the memory pipe idle most of the time (~50 us vs ~20 us floor). This round:
// double-buffered register batches -- issue batch k+1's 8 loads BEFORE
// consuming batch k, keeping ~16 KB in flight per wave continuously.

constexpr int Bc = 16;
constexpr int Tc = 4096;
constexpr int Hc = 512;
constexpr int CHUNK  = 64;           // tokens per block
constexpr int NCHUNK = Tc / CHUNK;   // 64 chunks per batch row
constexpr int NBLK   = Bc * NCHUNK;  // 1024 stage-1 blocks
constexpr int BW     = 8;            // batch width (tokens per register batch)

// ---------------- main path: partials, no atomics ----------------

// Block = 128 threads (2 waves); thread tid owns float4 column tid of H.
// Streams 64 tokens as 8 batches of 8, software-pipelined (double buffer).
__global__ __launch_bounds__(128) void glp_partial(
    const float* __restrict__ x,
    const int* __restrict__ lengths,
    const int* __restrict__ mask,   // int32 0/1
    float* __restrict__ pg,         // [NBLK][Hc] partial global sums
    float* __restrict__ pl,         // [NBLK][Hc] partial local sums
    int*   __restrict__ pcnt)       // [NBLK]     partial mask counts
{
    const int blk  = blockIdx.x;
    const int b    = blk >> 6;               // / NCHUNK
    const int c    = blk & (NCHUNK - 1);
    const int t0   = c * CHUNK;
    const int lane = threadIdx.x;            // 0..127 float4 column
    const int len  = lengths[b];

    const float4* __restrict__ xb =
        (const float4*)x + ((size_t)b * Tc + t0) * (Hc / 4) + lane;
    const int* __restrict__ mb = mask + (size_t)b * Tc + t0;  // uniform -> s_load

    float4 va[BW], vb[BW];
    int    ma[BW], mb2[BW];

    float4 g = make_float4(0.f, 0.f, 0.f, 0.f);
    float4 l = make_float4(0.f, 0.f, 0.f, 0.f);
    int mc = 0;

    // prologue: batch 0 -> va
    #pragma unroll
    for (int j = 0; j < BW; ++j) {
        va[j] = xb[(size_t)j * (Hc / 4)];
        ma[j] = mb[j];
    }

    #pragma unroll
    for (int p = 0; p < CHUNK / (2 * BW); ++p) {      // pairs of batches
        const int tA = 2 * p * BW;                     // tokens in va
        const int tB = tA + BW;                        // tokens for vb (always valid)
        // issue loads for batch tB BEFORE consuming va
        #pragma unroll
        for (int j = 0; j < BW; ++j) {
            vb[j]  = xb[(size_t)(tB + j) * (Hc / 4)];
            mb2[j] = mb[tB + j];
        }
        #pragma unroll
        for (int j = 0; j < BW; ++j) {
            const float wg = (t0 + tA + j < len) ? 1.f : 0.f;
            const float wl = ma[j] ? 1.f : 0.f;
            g.x = fmaf(va[j].x, wg, g.x); g.y = fmaf(va[j].y, wg, g.y);
            g.z = fmaf(va[j].z, wg, g.z); g.w = fmaf(va[j].w, wg, g.w);
            l.x = fmaf(va[j].x, wl, l.x); l.y = fmaf(va[j].y, wl, l.y);
            l.z = fmaf(va[j].z, wl, l.z); l.w = fmaf(va[j].w, wl, l.w);
            mc += (ma[j] != 0);
        }
        // issue loads for the NEXT pair's first batch before consuming vb
        if (p + 1 < CHUNK / (2 * BW)) {
            const int tC = tB + BW;
            #pragma unroll
            for (int j = 0; j < BW; ++j) {
                va[j] = xb[(size_t)(tC + j) * (Hc / 4)];
                ma[j] = mb[tC + j];
            }
        }
        #pragma unroll
        for (int j = 0; j < BW; ++j) {
            const float wg = (t0 + tB + j < len) ? 1.f : 0.f;
            const float wl = mb2[j] ? 1.f : 0.f;
            g.x = fmaf(vb[j].x, wg, g.x); g.y = fmaf(vb[j].y, wg, g.y);
            g.z = fmaf(vb[j].z, wg, g.z); g.w = fmaf(vb[j].w, wg, g.w);
            l.x = fmaf(vb[j].x, wl, l.x); l.y = fmaf(vb[j].y, wl, l.y);
            l.z = fmaf(vb[j].z, wl, l.z); l.w = fmaf(vb[j].w, wl, l.w);
            mc += (mb2[j] != 0);
        }
    }

    ((float4*)(pg + (size_t)blk * Hc))[lane] = g;   // coalesced 2 KB store
    ((float4*)(pl + (size_t)blk * Hc))[lane] = l;
    if (lane == 0) pcnt[blk] = mc;                  // mask uniform across lanes
}

// Stage 2: one block per b; reduce 64 partials per (b,h), divide, emit [B,2H].
__global__ __launch_bounds__(512) void glp_reduce(
    const float* __restrict__ pg,
    const float* __restrict__ pl,
    const int* __restrict__ pcnt,
    const int* __restrict__ lengths,
    float* __restrict__ out)
{
    const int b = blockIdx.x;
    const int h = threadIdx.x;
    const float* pgb = pg + (size_t)b * NCHUNK * Hc + h;
    const float* plb = pl + (size_t)b * NCHUNK * Hc + h;
    float gs = 0.f, ls = 0.f;
    #pragma unroll 8
    for (int c = 0; c < NCHUNK; ++c) {
        gs += pgb[(size_t)c * Hc];
        ls += plb[(size_t)c * Hc];
    }
    int cntv = 0;
    for (int c = 0; c < NCHUNK; ++c) cntv += pcnt[b * NCHUNK + c];  // uniform s_loads
    out[b * 2 * Hc + h]      = gs / (float)max(lengths[b], 1);
    out[b * 2 * Hc + Hc + h] = ls / (float)max(cntv, 1);
}

// ---------------- fallback path (ws too small): atomic version ----------------

__global__ __launch_bounds__(128) void glp_partial_atomic(
    const float* __restrict__ x,
    const int* __restrict__ lengths,
    const int* __restrict__ mask,
    float* __restrict__ gsum, float* __restrict__ lsum, int* __restrict__ cnt)
{
    const int blk  = blockIdx.x;
    const int b    = blk >> 6;
    const int c    = blk & (NCHUNK - 1);
    const int t0   = c * CHUNK;
    const int lane = threadIdx.x;
    const int len  = lengths[b];
    const float4* __restrict__ xb =
        (const float4*)x + ((size_t)b * Tc + t0) * (Hc / 4) + lane;
    const int* __restrict__ mb = mask + (size_t)b * Tc + t0;

    float4 g = make_float4(0.f, 0.f, 0.f, 0.f);
    float4 l = make_float4(0.f, 0.f, 0.f, 0.f);
    int mc = 0;
    for (int ii = 0; ii < CHUNK; ii += 8) {
        float4 v[8]; int m[8];
        #pragma unroll
        for (int j = 0; j < 8; ++j) { v[j] = xb[(size_t)(ii + j) * (Hc / 4)]; m[j] = mb[ii + j]; }
        #pragma unroll
        for (int j = 0; j < 8; ++j) {
            const float wg = (t0 + ii + j < len) ? 1.f : 0.f;
            const float wl = m[j] ? 1.f : 0.f;
            g.x = fmaf(v[j].x, wg, g.x); g.y = fmaf(v[j].y, wg, g.y);
            g.z = fmaf(v[j].z, wg, g.z); g.w = fmaf(v[j].w, wg, g.w);
            l.x = fmaf(v[j].x, wl, l.x); l.y = fmaf(v[j].y, wl, l.y);
            l.z = fmaf(v[j].z, wl, l.z); l.w = fmaf(v[j].w, wl, l.w);
            mc += (m[j] != 0);
        }
    }
    float* gp = gsum + b * Hc + lane * 4;
    float* lp = lsum + b * Hc + lane * 4;
    atomicAdd(gp + 0, g.x); atomicAdd(gp + 1, g.y);
    atomicAdd(gp + 2, g.z); atomicAdd(gp + 3, g.w);
    atomicAdd(lp + 0, l.x); atomicAdd(lp + 1, l.y);
    atomicAdd(lp + 2, l.z); atomicAdd(lp + 3, l.w);
    if (lane == 0) atomicAdd(cnt + b, mc);
}

__global__ __launch_bounds__(512) void glp_finalize(
    const float* __restrict__ gsum, const float* __restrict__ lsum,
    const int* __restrict__ cnt, const int* __restrict__ lengths,
    float* __restrict__ out)
{
    const int b = blockIdx.x;
    const int h = threadIdx.x;
    out[b * 2 * Hc + h]      = gsum[b * Hc + h] / (float)max(lengths[b], 1);
    out[b * 2 * Hc + Hc + h] = lsum[b * Hc + h] / (float)max(cnt[b], 1);
}

extern "C" void kernel_launch(void* const* d_in, const int* in_sizes, int n_in,
                              void* d_out, int out_size, void* d_ws, size_t ws_size,
                              hipStream_t stream) {
    const float* x     = (const float*)d_in[0];
    const int* lengths = (const int*)d_in[1];
    const int* mask    = (const int*)d_in[2];   // bool promoted to int32 by harness
    float* out = (float*)d_out;

    const size_t need = (size_t)NBLK * Hc * sizeof(float) * 2 + NBLK * sizeof(int);
    if (ws_size >= need) {
        float* pg  = (float*)d_ws;
        float* pl  = pg + (size_t)NBLK * Hc;
        int* pcnt  = (int*)(pl + (size_t)NBLK * Hc);
        glp_partial<<<NBLK, 128, 0, stream>>>(x, lengths, mask, pg, pl, pcnt);
        glp_reduce<<<Bc, Hc, 0, stream>>>(pg, pl, pcnt, lengths, out);
    } else {
        float* gsum = (float*)d_ws;
        float* lsum = gsum + Bc * Hc;
        int*   cnt  = (int*)(lsum + Bc * Hc);
        const size_t zb = (size_t)(2 * Bc * Hc) * sizeof(float) + Bc * sizeof(int);
        hipMemsetAsync(d_ws, 0, zb, stream);
        glp_partial_atomic<<<NBLK, 128, 0, stream>>>(x, lengths, mask, gsum, lsum, cnt);
        glp_finalize<<<Bc, Hc, 0, stream>>>(gsum, lsum, cnt, lengths, out);
    }
}